// Round 5
// baseline (405.277 us; speedup 1.0000x reference)
//
#include <hip/hip_runtime.h>

// SSIM loss — barrier-free streaming separable conv, v4 (resubmit; R4 bench
// died with a container-acquire infra error, same signature as R1 which
// passed unchanged on resubmit).
// v3 post-mortem: SROWS=16 added +24% halo work and zero concurrency
// (occupancy 16->18.9%, ~1.5 waves/SIMD); per-wave-step latency ~2900 cy with
// only 1 load in flight -> stretched to 268us. Per-wave LATENCY is the wall.
// v4: revert to SROWS=32 (v1 geometry, 122us) and attack per-step latency:
//  - TWO-DEEP prefetch: register sets pA (even steps) / pB (odd steps).
//    A row is fetched at step s and staged at step s+2 -> ~2 steps of latency
//    tolerance, 2 loads in flight at all times.
//  - Read-before-overwrite: each step issues its 12 window reads of buf[q]
//    FIRST, then stages row s+2 into the same buf[q] (in-order DS queue makes
//    this safe) -> no third buffer, and the reads no longer wait on any
//    same-step writes ahead of them in the queue.
//  - 22-step unrolled chunks (22 = 0 mod 11 and mod 2): step parity q and
//    ring slot u%11 are compile-time -> static LDS bases (no per-step par
//    select), static ring indexing (no scratch).
//  - Skewed LDS layout kept (v3 measured conflicts/step 104 -> 56).
//  - Fused finalize kept. __launch_bounds__(64,2) kept (NEVER (64,4): v2
//    spilled the 110-reg ring, 404MB scratch writes).

typedef float v2f __attribute__((ext_vector_type(2)));

#define IMG    512
#define SCOLS  128          // cols per strip (2 per lane)
#define SROWS  32           // output rows per strip
#define NSTEPS 42           // SROWS + 10 halo rows
#define BUFW   304          // skewed: 144 pairs + 8 pad pairs = 152 pairs = 304 words
#define NBLOCKS (4 * 16 * 48)
#define NPIX   (16.0f * 3.0f * 512.0f * 512.0f)

__device__ __forceinline__ float clamp01(float x) {
    // fmaxf(NaN,0) -> 0: nan_to_num + clip(0,1) in two ops
    return fminf(fmaxf(x, 0.0f), 1.0f);
}

__device__ __forceinline__ float ssim_px(v2f mu, v2f e, float e12, float C1, float C2) {
    v2f musq = mu * mu;                       // {mu1^2, mu2^2}  (pk_mul)
    float mu12 = mu.x * mu.y;
    v2f sig = e - musq;                       // {sig1, sig2}
    v2f lo = {1e-6f, 1e-6f};
    v2f hi = {1e6f, 1e6f};
    sig = __builtin_elementwise_max(sig, lo);
    sig = __builtin_elementwise_min(sig, hi);
    float s12 = e12 - mu12;
    float num = fmaf(2.f, mu12, C1) * fmaf(2.f, s12, C2);
    float den = (musq.x + musq.y + C1) * (sig.x + sig.y + C2);  // >= C1*C2 > 0
    return num * __builtin_amdgcn_rcpf(den);
}

__global__ __launch_bounds__(64, 2)   // (64,4) spilled the ring — never again
void ssim_stream_kernel(const float* __restrict__ imgA,
                        const float* __restrict__ imgB,
                        float* __restrict__ ws,
                        float* __restrict__ out)
{
    // Gaussian 11-tap, sigma=1.5, normalized (fp64-computed, verified R1)
    constexpr float GW[11] = {
        0.00102838f, 0.00759880f, 0.03600077f, 0.10936070f, 0.21300554f,
        0.26601173f,
        0.21300554f, 0.10936070f, 0.03600077f, 0.00759880f, 0.00102838f
    };
    const float C1 = 1.01e-4f;   // 0.01^2 + 1e-6
    const float C2 = 9.01e-4f;   // 0.03^2 + 1e-6

    __shared__ float sbuf[2][BUFW];   // 2432 B, parity double-buffer, skewed {a,b} pairs

    const int lane = threadIdx.x;
    const int C0 = blockIdx.x * SCOLS;
    const int R0 = blockIdx.y * SROWS;
    const size_t pOff = (size_t)blockIdx.z * (size_t)(IMG * IMG);

    // --- staging task decode (constant per lane) ---
    // 72 float4 tasks per row: t<36 -> imgA quad t ; t>=36 -> imgB quad t-36.
    // Skewed LDS word for col offset xr (= abs col - (C0-8)), img m:
    //   word = 2*(xr + (xr>>4)) + m.  Quad base 4q never crosses a 16-col
    //   skew block, so the 4 words are wd, wd+2, wd+4, wd+6.
    const int t0   = lane;
    const int q0   = (t0 < 36) ? t0 : (t0 - 36);
    const float* sp0 = ((t0 < 36) ? imgA : imgB) + pOff;
    const int col0 = C0 - 8 + 4 * q0;
    const bool okc0 = (col0 >= 0) && (col0 <= IMG - 4);   // quads never straddle edge
    const int wd0  = 8 * q0 + 2 * (q0 >> 2) + ((t0 < 36) ? 0 : 1);
    const bool has1 = (lane < 8);                          // tasks 64..71: imgB q=28..35
    const int q1   = 28 + lane;
    const int col1 = C0 - 8 + 4 * q1;
    const bool okc1 = (col1 >= 0) && (col1 <= IMG - 4);
    const int wd1  = 8 * q1 + 2 * (q1 >> 2) + 1;
    const float* sp1 = imgB + pOff;

    // --- precomputed skewed read offsets (words) for the 12 window pairs ---
    // pair index pw = 2*lane + 3 + p, word = 2*(pw + (pw>>4)), 8B-aligned.
    int rofs[12];
#pragma unroll
    for (int p = 0; p < 12; ++p) {
        const int pw = 2 * lane + 3 + p;
        rofs[p] = 2 * pw + 2 * (pw >> 4);
    }

    // --- register ring: 11 slots x 2 cols x {h1h2 pair, h11h22 pair, h12} ---
    v2f rA[11][2], rB[11][2];
    float rC[11][2];
#pragma unroll
    for (int i = 0; i < 11; ++i) {
        rA[i][0] = 0; rA[i][1] = 0;
        rB[i][0] = 0; rB[i][1] = 0;
        rC[i][0] = 0; rC[i][1] = 0;
    }

    float lsum = 0.f;
    float4 pA0, pA1, pB0, pB1;

#define FETCH(P0_, P1_, row_) do {                                            \
        const int ir = (row_);                                                \
        const bool okr = (unsigned)ir < (unsigned)IMG;                        \
        P0_ = make_float4(0,0,0,0); P1_ = make_float4(0,0,0,0);               \
        if (okr && okc0) P0_ = *(const float4*)(sp0 + (size_t)ir * IMG + col0);\
        if (has1 && okr && okc1)                                              \
            P1_ = *(const float4*)(sp1 + (size_t)ir * IMG + col1);            \
    } while (0)

#define STAGE(q_, P0_, P1_) do {                                              \
        float* d0 = &sbuf[q_][wd0];                                           \
        d0[0] = clamp01(P0_.x); d0[2] = clamp01(P0_.y);                       \
        d0[4] = clamp01(P0_.z); d0[6] = clamp01(P0_.w);                       \
        if (has1) {                                                           \
            float* d1 = &sbuf[q_][wd1];                                       \
            d1[0] = clamp01(P1_.x); d1[2] = clamp01(P1_.y);                   \
            d1[4] = clamp01(P1_.z); d1[6] = clamp01(P1_.w);                   \
        }                                                                     \
    } while (0)

    // One step. s_ runtime-uniform; U_ (ring slot = s mod 11) and Q_ (parity)
    // are compile-time via the 22-step unroll. Order inside a step:
    //   reads of buf[Q_] (row s)  ->  stage row s+2 into buf[Q_] (safe: DS
    //   queue is in-order per wave)  ->  fetch row s+4 (2-deep prefetch)
    //   ->  horizontal conv -> ring -> vertical conv + SSIM.
#define STEP(s_, U_, Q_, P0_, P1_) do {                                       \
        const int s = (s_);                                                   \
        if (s < NSTEPS) {                                                     \
            const float* sb = &sbuf[Q_][0];                                   \
            v2f w[12];                                                        \
            _Pragma("unroll")                                                 \
            for (int p = 0; p < 12; ++p)                                      \
                w[p] = *(const v2f*)(sb + rofs[p]);                           \
            if (s + 2 < NSTEPS) STAGE(Q_, P0_, P1_);                          \
            if (s + 4 < NSTEPS) FETCH(P0_, P1_, R0 - 5 + s + 4);              \
            v2f hA0 = 0, hB0 = 0, hA1 = 0, hB1 = 0;                           \
            float hC0 = 0, hC1 = 0;                                           \
            _Pragma("unroll")                                                 \
            for (int j = 0; j < 11; ++j) {                                    \
                const float gj = GW[j];                                       \
                v2f w0 = w[j], w1 = w[j + 1];                                 \
                v2f g0 = gj * w0;            /* {g*a, g*b}   pk_mul */        \
                v2f g1 = gj * w1;                                             \
                hA0 += g0; hA1 += g1;        /* {h1, h2}     pk_add */        \
                hB0 += g0 * w0;              /* {h11, h22}   pk_fma */        \
                hB1 += g1 * w1;                                               \
                hC0 = fmaf(g0.x, w0.y, hC0); /* h12          fma    */        \
                hC1 = fmaf(g1.x, w1.y, hC1);                                  \
            }                                                                 \
            rA[U_][0] = hA0; rA[U_][1] = hA1;                                 \
            rB[U_][0] = hB0; rB[U_][1] = hB1;                                 \
            rC[U_][0] = hC0; rC[U_][1] = hC1;                                 \
            if (s >= 10) {                                                    \
                v2f vA0 = 0, vB0 = 0, vA1 = 0, vB1 = 0;                       \
                float vC0 = 0, vC1 = 0;                                       \
                _Pragma("unroll")                                             \
                for (int i = 0; i < 11; ++i) {                                \
                    const int sl = ((U_) + 1 + i) % 11;  /* slot of s-10+i */ \
                    const float gi = GW[i];                                   \
                    vA0 += gi * rA[sl][0]; vA1 += gi * rA[sl][1];             \
                    vB0 += gi * rB[sl][0]; vB1 += gi * rB[sl][1];             \
                    vC0 = fmaf(gi, rC[sl][0], vC0);                           \
                    vC1 = fmaf(gi, rC[sl][1], vC1);                           \
                }                                                             \
                lsum += ssim_px(vA0, vB0, vC0, C1, C2);                       \
                lsum += ssim_px(vA1, vB1, vC1, C1, C2);                       \
            }                                                                 \
        }                                                                     \
    } while (0)

    // --- prologue: rows 0,1 staged; rows 2,3 in flight (2-deep) ---
    FETCH(pA0, pA1, R0 - 5);            // row 0
    FETCH(pB0, pB1, R0 - 4);            // row 1
    STAGE(0, pA0, pA1);
    FETCH(pA0, pA1, R0 - 3);            // row 2
    STAGE(1, pB0, pB1);
    FETCH(pB0, pB1, R0 - 2);            // row 3

#pragma unroll 1
    for (int ch = 0; ch < 2; ++ch) {
#pragma unroll
        for (int uh = 0; uh < 11; ++uh) {
            STEP(ch * 22 + 2 * uh,     (2 * uh) % 11,     0, pA0, pA1);
            STEP(ch * 22 + 2 * uh + 1, (2 * uh + 1) % 11, 1, pB0, pB1);
        }
    }
#undef STEP
#undef FETCH
#undef STAGE

    // wave64 reduce, one atomic per wave
#pragma unroll
    for (int off = 32; off >= 1; off >>= 1)
        lsum += __shfl_down(lsum, off, 64);

    if (lane == 0) {
        atomicAdd(ws, lsum);
        __threadfence();
        unsigned done = atomicAdd(reinterpret_cast<unsigned*>(ws) + 1, 1u);
        if (done == NBLOCKS - 1) {
            __threadfence();
            float total = atomicAdd(ws, 0.0f);   // coherent read-back
            out[0] = 1.0f - total * (1.0f / NPIX);
        }
    }
}

extern "C" void kernel_launch(void* const* d_in, const int* in_sizes, int n_in,
                              void* d_out, int out_size, void* d_ws, size_t ws_size,
                              hipStream_t stream) {
    const float* img1 = (const float*)d_in[0];
    const float* img2 = (const float*)d_in[1];
    float* out = (float*)d_out;
    float* ws  = (float*)d_ws;

    hipMemsetAsync(ws, 0, 2 * sizeof(float), stream);   // {sum, done-counter}

    dim3 grid(IMG / SCOLS, IMG / SROWS, 48);            // 4 x 16 x 48 = 3072 waves
    ssim_stream_kernel<<<grid, 64, 0, stream>>>(img1, img2, ws, out);
}

// Round 6
// 263.089 us; speedup vs baseline: 1.5405x; 1.5405x over previous
//
#include <hip/hip_runtime.h>

// SSIM loss — barrier-free streaming separable conv, v5.
// v4 post-mortem: full 22-step static unroll blew register pressure (VGPR
// capped at 128, 234MB scratch writes) -> revert to v1's spill-free skeleton
// (11-step unroll, dynamic par, 100-112 VGPR). v5 changes exactly three things:
//  1. 4 waves per 256-thread block, each wave owns its own 32-row strip and a
//     private LDS slice (no sharing, no barriers). 768 blocks = 3 blocks/CU
//     -> 12 waves/CU forced resident (1-wave blocks only reached ~5: v1/v3).
//  2. T14 issue-early/write-late step order: LDS reads of row s -> FETCH row
//     s+1 (stays in flight under the whole conv) -> conv/SSIM -> STAGE into
//     the other buffer. Removes v1's top-of-step vmcnt stall; p's live range
//     is now intra-step (less pressure).
//  3. Skewed LDS layout kept (measured conflicts/step 104 -> 56).
// __launch_bounds__(256,2) = VGPR cap 256; never cap at 4 waves/EU (v2 spill).

typedef float v2f __attribute__((ext_vector_type(2)));

#define IMG    512
#define SCOLS  128          // cols per strip (2 per lane)
#define SROWS  32           // output rows per strip (per wave)
#define NSTEPS 42           // SROWS + 10 halo rows
#define BUFW   304          // skewed: 144 pairs + 8 pad pairs = 152 pairs = 304 words
#define WPB    4            // waves per block
#define NBLOCKS (4 * 4 * 48)
#define NWAVES  (NBLOCKS * WPB)
#define NPIX   (16.0f * 3.0f * 512.0f * 512.0f)

__device__ __forceinline__ float clamp01(float x) {
    // fmaxf(NaN,0) -> 0: nan_to_num + clip(0,1) in two ops
    return fminf(fmaxf(x, 0.0f), 1.0f);
}

__device__ __forceinline__ float ssim_px(v2f mu, v2f e, float e12, float C1, float C2) {
    v2f musq = mu * mu;                       // {mu1^2, mu2^2}  (pk_mul)
    float mu12 = mu.x * mu.y;
    v2f sig = e - musq;                       // {sig1, sig2}
    v2f lo = {1e-6f, 1e-6f};
    v2f hi = {1e6f, 1e6f};
    sig = __builtin_elementwise_max(sig, lo);
    sig = __builtin_elementwise_min(sig, hi);
    float s12 = e12 - mu12;
    float num = fmaf(2.f, mu12, C1) * fmaf(2.f, s12, C2);
    float den = (musq.x + musq.y + C1) * (sig.x + sig.y + C2);  // >= C1*C2 > 0
    return num * __builtin_amdgcn_rcpf(den);
}

__global__ __launch_bounds__(256, 2)
void ssim_stream_kernel(const float* __restrict__ imgA,
                        const float* __restrict__ imgB,
                        float* __restrict__ ws,
                        float* __restrict__ out)
{
    // Gaussian 11-tap, sigma=1.5, normalized (fp64-computed, verified R1)
    constexpr float GW[11] = {
        0.00102838f, 0.00759880f, 0.03600077f, 0.10936070f, 0.21300554f,
        0.26601173f,
        0.21300554f, 0.10936070f, 0.03600077f, 0.00759880f, 0.00102838f
    };
    const float C1 = 1.01e-4f;   // 0.01^2 + 1e-6
    const float C2 = 9.01e-4f;   // 0.03^2 + 1e-6

    // Per-wave private double buffer, skewed {a,b} pairs. 4 x 2432 B = 9728 B.
    __shared__ float sbuf[WPB][2][BUFW];

    const int tid  = threadIdx.x;
    const int wid  = tid >> 6;
    const int lane = tid & 63;
    const int C0 = blockIdx.x * SCOLS;
    const int R0 = (blockIdx.y * WPB + wid) * SROWS;
    const size_t pOff = (size_t)blockIdx.z * (size_t)(IMG * IMG);

    float* const sbase0 = &sbuf[wid][0][0];
    float* const sbase1 = &sbuf[wid][1][0];

    // --- staging task decode (constant per lane) ---
    // 72 float4 tasks per row: t<36 -> imgA quad t ; t>=36 -> imgB quad t-36.
    // Skewed LDS word for col offset xr (= abs col - (C0-8)), img m:
    //   word = 2*(xr + (xr>>4)) + m.  Quad base 4q never crosses a 16-col
    //   skew block, so the 4 words are wd, wd+2, wd+4, wd+6.
    const int t0   = lane;
    const int q0   = (t0 < 36) ? t0 : (t0 - 36);
    const float* sp0 = ((t0 < 36) ? imgA : imgB) + pOff;
    const int col0 = C0 - 8 + 4 * q0;
    const bool okc0 = (col0 >= 0) && (col0 <= IMG - 4);   // quads never straddle edge
    const int wd0  = 8 * q0 + 2 * (q0 >> 2) + ((t0 < 36) ? 0 : 1);
    const bool has1 = (lane < 8);                          // tasks 64..71: imgB q=28..35
    const int q1   = 28 + lane;
    const int col1 = C0 - 8 + 4 * q1;
    const bool okc1 = (col1 >= 0) && (col1 <= IMG - 4);
    const int wd1  = 8 * q1 + 2 * (q1 >> 2) + 1;
    const float* sp1 = imgB + pOff;

    // --- precomputed skewed read offsets (words) for the 12 window pairs ---
    // pair index pw = 2*lane + 3 + p, word = 2*(pw + (pw>>4)), 8B-aligned.
    int rofs[12];
#pragma unroll
    for (int p = 0; p < 12; ++p) {
        const int pw = 2 * lane + 3 + p;
        rofs[p] = 2 * pw + 2 * (pw >> 4);
    }

    // --- register ring: 11 slots x 2 cols x {h1h2 pair, h11h22 pair, h12} ---
    v2f rA[11][2], rB[11][2];
    float rC[11][2];
#pragma unroll
    for (int i = 0; i < 11; ++i) {
        rA[i][0] = 0; rA[i][1] = 0;
        rB[i][0] = 0; rB[i][1] = 0;
        rC[i][0] = 0; rC[i][1] = 0;
    }

    float lsum = 0.f;
    float4 p0, p1;

#define FETCH(row_) do {                                                      \
        const int ir = (row_);                                                \
        const bool okr = (unsigned)ir < (unsigned)IMG;                        \
        p0 = make_float4(0,0,0,0); p1 = make_float4(0,0,0,0);                 \
        if (okr && okc0) p0 = *(const float4*)(sp0 + (size_t)ir * IMG + col0);\
        if (has1 && okr && okc1)                                              \
            p1 = *(const float4*)(sp1 + (size_t)ir * IMG + col1);             \
    } while (0)

#define STAGE(dbase_) do {                                                    \
        float* d0 = (dbase_) + wd0;                                           \
        d0[0] = clamp01(p0.x); d0[2] = clamp01(p0.y);                         \
        d0[4] = clamp01(p0.z); d0[6] = clamp01(p0.w);                         \
        if (has1) {                                                           \
            float* d1 = (dbase_) + wd1;                                       \
            d1[0] = clamp01(p1.x); d1[2] = clamp01(p1.y);                     \
            d1[4] = clamp01(p1.z); d1[6] = clamp01(p1.w);                     \
        }                                                                     \
    } while (0)

    // --- prologue: row 0 staged into buf0 ---
    FETCH(R0 - 5);
    STAGE(sbase0);

#pragma unroll 1
    for (int ch = 0; ch < 4; ++ch) {
#pragma unroll
        for (int u = 0; u < 11; ++u) {
            const int s = ch * 11 + u;          // uniform across wave
            if (s < NSTEPS) {
                const int par = s & 1;
                const float* sb = par ? sbase1 : sbase0;   // holds row s
                float* db       = par ? sbase0 : sbase1;   // gets row s+1

                // 1. window read (12 skewed v2f) of row s — issued first
                v2f w[12];
#pragma unroll
                for (int p = 0; p < 12; ++p)
                    w[p] = *(const v2f*)(sb + rofs[p]);

                // 2. issue fetch of row s+1 — in flight under the whole conv
                if (s + 1 < NSTEPS) FETCH(R0 - 5 + s + 1);

                // 3. horizontal conv (packed) -> ring slot u
                {
                    v2f hA0 = 0, hB0 = 0, hA1 = 0, hB1 = 0;
                    float hC0 = 0, hC1 = 0;
#pragma unroll
                    for (int j = 0; j < 11; ++j) {
                        const float gj = GW[j];
                        v2f w0 = w[j], w1 = w[j + 1];
                        v2f g0 = gj * w0;            // {g*a, g*b}   pk_mul
                        v2f g1 = gj * w1;
                        hA0 += g0; hA1 += g1;        // {h1, h2}     pk_add
                        hB0 += g0 * w0;              // {h11, h22}   pk_fma
                        hB1 += g1 * w1;
                        hC0 = fmaf(g0.x, w0.y, hC0); // h12          fma
                        hC1 = fmaf(g1.x, w1.y, hC1);
                    }
                    rA[u][0] = hA0; rA[u][1] = hA1;
                    rB[u][0] = hB0; rB[u][1] = hB1;
                    rC[u][0] = hC0; rC[u][1] = hC1;
                }

                // 4. vertical conv from ring + SSIM (out row R0+s-10)
                if (s >= 10) {
                    v2f vA0 = 0, vB0 = 0, vA1 = 0, vB1 = 0;
                    float vC0 = 0, vC1 = 0;
#pragma unroll
                    for (int i = 0; i < 11; ++i) {
                        const int sl = (u + 1 + i) % 11;   // slot of step s-10+i (static)
                        const float gi = GW[i];
                        vA0 += gi * rA[sl][0]; vA1 += gi * rA[sl][1];
                        vB0 += gi * rB[sl][0]; vB1 += gi * rB[sl][1];
                        vC0 = fmaf(gi, rC[sl][0], vC0);
                        vC1 = fmaf(gi, rC[sl][1], vC1);
                    }
                    lsum += ssim_px(vA0, vB0, vC0, C1, C2);
                    lsum += ssim_px(vA1, vB1, vC1, C1, C2);
                }

                // 5. write-late: stage row s+1 into the other buffer (the
                //    vmcnt wait lands here, after ~a full conv of flight time)
                if (s + 1 < NSTEPS) STAGE(db);
            }
        }
    }
#undef FETCH
#undef STAGE

    // wave64 reduce, one atomic per wave (4 per block)
#pragma unroll
    for (int off = 32; off >= 1; off >>= 1)
        lsum += __shfl_down(lsum, off, 64);

    if (lane == 0) {
        atomicAdd(ws, lsum);
        __threadfence();
        unsigned done = atomicAdd(reinterpret_cast<unsigned*>(ws) + 1, 1u);
        if (done == NWAVES - 1) {
            __threadfence();
            float total = atomicAdd(ws, 0.0f);   // coherent read-back
            out[0] = 1.0f - total * (1.0f / NPIX);
        }
    }
}

extern "C" void kernel_launch(void* const* d_in, const int* in_sizes, int n_in,
                              void* d_out, int out_size, void* d_ws, size_t ws_size,
                              hipStream_t stream) {
    const float* img1 = (const float*)d_in[0];
    const float* img2 = (const float*)d_in[1];
    float* out = (float*)d_out;
    float* ws  = (float*)d_ws;

    hipMemsetAsync(ws, 0, 2 * sizeof(float), stream);   // {sum, done-counter}

    dim3 grid(IMG / SCOLS, IMG / (SROWS * WPB), 48);    // 4 x 4 x 48 = 768 blocks
    ssim_stream_kernel<<<grid, 64 * WPB, 0, stream>>>(img1, img2, ws, out);
}